// Round 8
// baseline (76.188 us; speedup 1.0000x reference)
//
#include <hip/hip_runtime.h>
#include <math.h>

// Problem constants
#define NQ 10
#define DIM 1024          // 2^10
#define NPTS 64
#define DFEAT 10
#define NLAYERS 5
#define SREGS 4           // amps per thread (DIM / 256)
#define NPAIR 2080        // 64*65/2 upper-triangle pairs
#define GBLK  (NPAIR / 4) // 520 gram blocks, 4 waves each

#define IS2 0.70710678118654752440f

// ws layout: psi (64*1024 float2 = 512 KB) | partials (2*GBLK floats)
#define PART_OFF ((size_t)NPTS * DIM * sizeof(float2))

// ---------------------------------------------------------------------------
// Kernel 1: psi_i = U(x_i)|0>. 64 blocks (one per data point) x 256 threads.
// Amp index idx = (r<<8)|(wv<<6)|lane: bits 0..5 lane (shfl_xor, batched
// 8-deep across 4 amps), bits 6..7 wave (LDS exchange, SINGLE barrier via
// double-buffering), bits 8..9 register (pure VALU butterfly).
//
// Lessons encoded:
//  R2: batch independent DS ops (4 amps/thread -> 8 shuffles issued together)
//  R4: keep loops ROLLED (unrolled = I-fetch bound, FETCH ~= 8 XCDs x code)
//  R6: no single-address device atomics
//  R7: barriers dominate state (32 syncs); double-buffer -> 8 total.
//      Double-buffer safety: a thread re-writing buf p has passed the NEXT
//      stage's barrier; every thread's read of old buf p precedes that
//      barrier in program order.
//
// Verified algebra (absmax==0, R4-R7):
//  fused 1q gate M = RY(t)*RZ(x)*H, x angle = x[9-q] every layer
//  (all starts % 10 == 0). cx=cos(x/2), sx=sin(x/2), c=cos(t/2), s=sin(t/2),
//  p=(c+s)/sqrt2, q=(c-s)/sqrt2:
//    m00=(q*cx,-p*sx) m01=(p*cx,-q*sx) m10=conj(m01) m11=-conj(m00)
//  layer 0 acts on |0> -> product state (no exchanges);
//  layer 5 ring + RY are data-independent outer unitaries -> cancel in
//  |<psi_j|psi_i>|^2 (c=1,s=0; ring skipped).
// ---------------------------------------------------------------------------
__global__ __launch_bounds__(256) void state_kernel(
    const float* __restrict__ data,     // (64,10)
    const float* __restrict__ params,   // (5,2,10)
    float2* __restrict__ psi)           // (64,1024)
{
    const int i    = blockIdx.x;
    const int tid  = threadIdx.x;
    const int lane = tid & 63;
    const int wv   = tid >> 6;

    __shared__ float4 mc[NLAYERS][NQ];     // (m00r, m00i, m01r, m01i)
    __shared__ float2 xb[2][16][64];       // double-buffered exchange (16 KB)

    // ---- precompute fused gate coefficients (50 threads, once) ----
    if (tid < NLAYERS * NQ) {
        const int L = tid / NQ, q = tid - L * NQ;
        const float xh = 0.5f * data[i * DFEAT + (9 - q)];
        const float cx = __cosf(xh), sx = __sinf(xh);
        float c = 1.f, s = 0.f;
        if (L != NLAYERS - 1) {
            const float th = 0.5f * params[L * 2 * NQ + q];
            c = __cosf(th); s = __sinf(th);
        }
        const float p = (c + s) * IS2, qm = (c - s) * IS2;
        mc[L][q] = make_float4(qm * cx, -p * sx, p * cx, -qm * sx);
    }
    __syncthreads();

    float re[SREGS], im[SREGS];

    // ---- layer 0: product state (no exchanges) ----
    {
        float Pr = 1.f, Pi = 0.f;          // bits 0..7 (lane + wave)
#pragma unroll 1
        for (int q = 0; q < 8; ++q) {
            const float4 m = mc[0][q];
            const int b = (q < 6) ? ((lane >> q) & 1) : ((wv >> (q - 6)) & 1);
            const float fr = b ? m.z : m.x;          // u1=m10, u0=m00
            const float fi = b ? -m.w : m.y;
            const float nr = Pr * fr - Pi * fi;
            const float ni = Pr * fi + Pi * fr;
            Pr = nr; Pi = ni;
        }
        const float4 m8 = mc[0][8], m9 = mc[0][9];
        const float u8r[2] = {m8.x, m8.z}, u8i[2] = {m8.y, -m8.w};
        const float u9r[2] = {m9.x, m9.z}, u9i[2] = {m9.y, -m9.w};
#pragma unroll
        for (int r = 0; r < SREGS; ++r) {
            const int b8 = r & 1, b9 = (r >> 1) & 1;
            const float vr = u8r[b8] * u9r[b9] - u8i[b8] * u9i[b9];
            const float vi = u8r[b8] * u9i[b9] + u8i[b8] * u9r[b9];
            re[r] = Pr * vr - Pi * vi;
            im[r] = Pr * vi + Pi * vr;
        }
    }

    int sp = 0;   // exchange-buffer parity

#pragma unroll 1
    for (int L = 0; L < NLAYERS; ++L) {
        if (L > 0) {
            // ---- qubits 0..5: cross-lane butterfly, 8 shuffles batched ----
#pragma unroll 1
            for (int q = 0; q < 6; ++q) {
                const float4 m = mc[L][q];
                const int   b = (lane >> q) & 1;
                const float msr = b ? -m.x : m.x;   // m11r / m00r
                const float msi = m.y;              // m11i == m00i
                const float mpr = m.z;              // m10r == m01r
                const float mpi = b ? -m.w : m.w;   // m10i / m01i
                float pr[SREGS], pi[SREGS];
#pragma unroll
                for (int r = 0; r < SREGS; ++r) {
                    pr[r] = __shfl_xor(re[r], 1 << q, 64);
                    pi[r] = __shfl_xor(im[r], 1 << q, 64);
                }
#pragma unroll
                for (int r = 0; r < SREGS; ++r) {
                    const float nr = msr * re[r] - msi * im[r] + mpr * pr[r] - mpi * pi[r];
                    const float ni = msr * im[r] + msi * re[r] + mpr * pi[r] + mpi * pr[r];
                    re[r] = nr; im[r] = ni;
                }
            }

            // ---- qubits 6..7: cross-wave via LDS, ONE barrier per stage ----
#pragma unroll 1
            for (int q = 6; q < 8; ++q) {
                const float4 m = mc[L][q];
                const int   b = (wv >> (q - 6)) & 1;
                const float msr = b ? -m.x : m.x;
                const float msi = m.y;
                const float mpr = m.z;
                const float mpi = b ? -m.w : m.w;
#pragma unroll
                for (int r = 0; r < SREGS; ++r)
                    xb[sp][(wv << 2) | r][lane] = make_float2(re[r], im[r]);
                __syncthreads();
                const int pw = wv ^ (1 << (q - 6));
#pragma unroll
                for (int r = 0; r < SREGS; ++r) {
                    const float2 p2 = xb[sp][(pw << 2) | r][lane];
                    const float nr = msr * re[r] - msi * im[r] + mpr * p2.x - mpi * p2.y;
                    const float ni = msr * im[r] + msi * re[r] + mpr * p2.y + mpi * p2.x;
                    re[r] = nr; im[r] = ni;
                }
                sp ^= 1;   // next stage uses the other buffer — no 2nd barrier
            }

            // ---- qubits 8..9: in-register butterfly (no DS, no barrier) ----
#pragma unroll
            for (int q = 8; q < 10; ++q) {
                const int mask = 1 << (q - 8);
                const float4 m = mc[L][q];
                const float m00r = m.x, m00i = m.y, m01r = m.z, m01i = m.w;
                const float m10r = m.z, m10i = -m.w, m11r = -m.x, m11i = m.y;
#pragma unroll
                for (int r = 0; r < SREGS; ++r) {
                    if (!(r & mask)) {
                        const int r1 = r | mask;
                        const float a0r = re[r],  a0i = im[r];
                        const float a1r = re[r1], a1i = im[r1];
                        re[r]  = m00r * a0r - m00i * a0i + m01r * a1r - m01i * a1i;
                        im[r]  = m00r * a0i + m00i * a0r + m01r * a1i + m01i * a1r;
                        re[r1] = m10r * a0r - m10i * a0i + m11r * a1r - m11i * a1i;
                        im[r1] = m10r * a0i + m10i * a0r + m11r * a1i + m11i * a1r;
                    }
                }
            }
        }

        // ---- crz ring diagonal (skip layer 5: cancels) ----
        if (L < NLAYERS - 1) {
            const float* rg = params + L * 2 * NQ + NQ;
            float ph[SREGS] = {0.f, 0.f, 0.f, 0.f};
#pragma unroll 1
            for (int n = 0; n < NQ; ++n) {
                const int   nn = (n == 9) ? 0 : (n + 1);
                const float g  = rg[n];     // wave-uniform -> s_load
#pragma unroll
                for (int r = 0; r < SREGS; ++r) {
                    const int idx = (r << 8) | (wv << 6) | lane;
                    const float t = (((idx >> nn) & 1) ? 0.5f : -0.5f) * g;
                    ph[r] += ((idx >> n) & 1) ? t : 0.f;
                }
            }
#pragma unroll
            for (int r = 0; r < SREGS; ++r) {
                const float s = __sinf(ph[r]), c = __cosf(ph[r]);
                const float nr = re[r] * c - im[r] * s;
                const float ni = re[r] * s + im[r] * c;
                re[r] = nr; im[r] = ni;
            }
        }
    }

    // write psi_i (coalesced float2)
    float2* out = psi + i * DIM;
#pragma unroll
    for (int r = 0; r < SREGS; ++r)
        out[(r << 8) | (wv << 6) | lane] = make_float2(re[r], im[r]);
}

// ---------------------------------------------------------------------------
// Kernel 2: gram partials over the UPPER TRIANGLE only (unchanged from R7).
// Wave w -> pair (i,j), j>=i, closed-form triangle indexing. Off-diagonals
// weighted 2. Block partials written unconditionally -> no init needed.
// ---------------------------------------------------------------------------
__global__ __launch_bounds__(256) void gram_kernel(
    const float4* __restrict__ psi4,    // (64, 512) float4 view of psi
    const float* __restrict__ labels,   // (64,)
    float* __restrict__ partials)       // (2*GBLK,)
{
    __shared__ float sm[2][4];
    const int wave = threadIdx.x >> 6;
    const int lane = threadIdx.x & 63;
    const int w    = blockIdx.x * 4 + wave;   // 0..2079

    int i = (int)((129.0f - sqrtf(16641.0f - 8.0f * (float)w)) * 0.5f);
    int Ci = 64 * i - ((i * (i - 1)) >> 1);
    while (w < Ci)            { --i; Ci = 64 * i - ((i * (i - 1)) >> 1); }
    while (w >= Ci + 64 - i)  { Ci += 64 - i; ++i; }
    const int j = i + (w - Ci);

    const float4* a = psi4 + i * (DIM / 2);
    const float4* b = psi4 + j * (DIM / 2);

    float zr = 0.f, zi = 0.f;   // <psi_j|psi_i> = sum conj(b)*a
#pragma unroll
    for (int r = 0; r < 8; ++r) {
        const int k = (r << 6) | lane;
        const float4 av = a[k], bv = b[k];
        zr += bv.x * av.x + bv.y * av.y + bv.z * av.z + bv.w * av.w;
        zi += bv.x * av.y - bv.y * av.x + bv.z * av.w - bv.w * av.z;
    }
#pragma unroll
    for (int off = 32; off; off >>= 1) {
        zr += __shfl_xor(zr, off, 64);
        zi += __shfl_xor(zi, off, 64);
    }

    if (lane == 0) {
        const float k = zr * zr + zi * zi;
        const float wgt = (i == j) ? 1.f : 2.f;
        sm[0][wave] = wgt * labels[i] * labels[j] * k;
        sm[1][wave] = wgt * k * k;
    }
    __syncthreads();
    if (threadIdx.x == 0) {
        partials[2 * blockIdx.x]     = sm[0][0] + sm[0][1] + sm[0][2] + sm[0][3];
        partials[2 * blockIdx.x + 1] = sm[1][0] + sm[1][1] + sm[1][2] + sm[1][3];
    }
}

// ---------------------------------------------------------------------------
// Kernel 3: final KTA (unchanged from R7).
// ---------------------------------------------------------------------------
__global__ __launch_bounds__(256) void reduce_kernel(
    const float* __restrict__ partials,
    const float* __restrict__ labels,
    float* __restrict__ out)
{
    __shared__ float sm[3][4];
    const int tid  = threadIdx.x;
    const int lane = tid & 63;
    const int wave = tid >> 6;

    float slk = 0.f, skk = 0.f, sl2 = 0.f;
    for (int p = tid; p < GBLK; p += 256) {
        slk += partials[2 * p];
        skk += partials[2 * p + 1];
    }
    if (tid < NPTS) { const float l = labels[tid]; sl2 = l * l; }

#pragma unroll
    for (int off = 32; off; off >>= 1) {
        slk += __shfl_xor(slk, off, 64);
        skk += __shfl_xor(skk, off, 64);
        sl2 += __shfl_xor(sl2, off, 64);
    }
    if (lane == 0) { sm[0][wave] = slk; sm[1][wave] = skk; sm[2][wave] = sl2; }
    __syncthreads();
    if (tid == 0) {
        const float a = sm[0][0] + sm[0][1] + sm[0][2] + sm[0][3];
        const float b = sm[1][0] + sm[1][1] + sm[1][2] + sm[1][3];
        const float c = sm[2][0] + sm[2][1] + sm[2][2] + sm[2][3];
        out[0] = a / sqrtf(b * (c * c));
    }
}

extern "C" void kernel_launch(void* const* d_in, const int* in_sizes, int n_in,
                              void* d_out, int out_size, void* d_ws, size_t ws_size,
                              hipStream_t stream) {
    const float* data   = (const float*)d_in[0];  // (64,10)
    const float* labels = (const float*)d_in[1];  // (64,)
    const float* params = (const float*)d_in[2];  // (5,2,10)
    float* out = (float*)d_out;

    float2* psi      = (float2*)d_ws;
    float*  partials = (float*)((char*)d_ws + PART_OFF);

    state_kernel <<<NPTS,  256, 0, stream>>>(data, params, psi);
    gram_kernel  <<<GBLK,  256, 0, stream>>>((const float4*)psi, labels, partials);
    reduce_kernel<<<1,     256, 0, stream>>>(partials, labels, out);
}